// Round 4
// baseline (369.841 us; speedup 1.0000x reference)
//
#include <hip/hip_runtime.h>

typedef unsigned short ushort_t;
typedef unsigned int uint32;
typedef __bf16 bf16x8 __attribute__((ext_vector_type(8)));
typedef float f32x4 __attribute__((ext_vector_type(4)));

#define NTOK 128
#define DIMX 180
#define NH 6
#define HD 30
#define NWIN 64

__device__ __forceinline__ ushort_t f2bf(float f){
  uint32 u = __float_as_uint(f);
  u += 0x7FFFu + ((u >> 16) & 1u);
  return (ushort_t)(u >> 16);
}
__device__ __forceinline__ float bf2f(ushort_t h){
  return __uint_as_float(((uint32)h) << 16);
}
__device__ __forceinline__ f32x4 mfma16(bf16x8 a, bf16x8 b, f32x4 c){
  return __builtin_amdgcn_mfma_f32_16x16x32_bf16(a, b, c, 0, 0, 0);
}

// ---------------- prep kernels ----------------

// wqkvP fragment-contiguous: element ((ct_g*6+ks)*64 + lane)*8 + e
//   = w-col oc=ct_g*16+(lane&15) [oc=(sel*6+head)*32+d], k = ks*32+(lane>>4)*8+e
__global__ void prep_wqkv(const float* __restrict__ w, ushort_t* __restrict__ o){
  int blk = blockIdx.x;               // ct_g*6 + ks, 216 blocks
  int ct_g = blk / 6, ks = blk - ct_g*6;
  int lane = threadIdx.x;             // 64
  int l16 = lane & 15, lq = lane >> 4;
  int oc = ct_g*16 + l16;
  int seg = oc >> 5, dd = oc & 31;
  int sel = seg / NH, head = seg % NH;
  ushort_t vals[8];
  #pragma unroll
  for (int e = 0; e < 8; e++){
    int k = ks*32 + lq*8 + e;
    float v = 0.f;
    if (dd < HD && k < DIMX) v = w[k*(3*DIMX) + sel*DIMX + head*HD + dd];
    vals[e] = f2bf(v);
  }
  *reinterpret_cast<uint4*>(&o[((size_t)blk*64 + lane)*8]) =
      *reinterpret_cast<const uint4*>(vals);
}

// wfcP: 3 K-chunks of 64, XOR-swizzled linear image for conflict-free ds_read_b128:
//   elem idx = c*12288 + ((oc*64 + kk) ^ ((oc&7)<<3)),  oc=out col (192), kk=k%64
__global__ void prep_wfc(const float* __restrict__ w, ushort_t* __restrict__ o){
  int oc = blockIdx.x, k = threadIdx.x;   // 192 x 192
  float v = (oc < DIMX && k < DIMX) ? w[k*DIMX + oc] : 0.f;
  int c = k >> 6, kk = k & 63;
  int idx = c*12288 + ((oc*64 + kk) ^ ((oc & 7) << 3));
  o[idx] = f2bf(v);
}

// bias_p in MFMA C-fragment order (unchanged from round 3)
__global__ void prep_bias(const float* __restrict__ rpt, const float* __restrict__ mask,
                          const int* __restrict__ rpi, ushort_t* __restrict__ o){
  int blk = blockIdx.x;            // (w*6+h)*8 + wave
  int wave = blk & 7, wh = blk >> 3;
  int h = wh % NH, w = wh / NH;
  int i = threadIdx.x;             // 512
  int lane = i >> 3, t = i & 7;
  int l16 = lane & 15, lq = lane >> 4;
  int m = t*16 + l16;
  ushort_t vals[4];
  #pragma unroll
  for (int r = 0; r < 4; r++){
    int n = wave*16 + lq*4 + r;
    float v = rpt[rpi[n*NTOK + m]*NH + h] + mask[((size_t)w*NTOK + n)*NTOK + m];
    vals[r] = f2bf(v);
  }
  *reinterpret_cast<uint2*>(&o[((size_t)blk*64 + lane)*32 + t*4]) =
      *reinterpret_cast<const uint2*>(vals);
}

// ---------------- QKV projection ----------------
// grid 2048 (64 rows each), 512 thr, waves 2x4, wave tile 32x144.
// LDS 51200 B: xs [64][200]; epilogue quarters aliased: cqk [16][392] + cv [192][24].
__global__ __launch_bounds__(512, 4) void qkv_kernel(
    const float* __restrict__ x, const ushort_t* __restrict__ wqkvP,
    const float* __restrict__ b_qkv,
    ushort_t* __restrict__ Qo, ushort_t* __restrict__ Ko, ushort_t* __restrict__ Vo)
{
  __shared__ ushort_t sm[25600];
  ushort_t* xs  = sm;            // [64][200]
  ushort_t* cqk = sm;            // [16][392]  (alias, epilogue)
  ushort_t* cv  = sm + 6272;     // [192][24]  (alias, epilogue)

  const int tid = threadIdx.x;
  const float* xb = x + (size_t)blockIdx.x * 64 * DIMX;

  for (int c = tid; c < 64*45; c += 512){
    int row = c / 45, c4 = (c % 45) * 4;
    float4 f = reinterpret_cast<const float4*>(xb)[c];
    uint32 lo = ((uint32)f2bf(f.y) << 16) | f2bf(f.x);
    uint32 hi = ((uint32)f2bf(f.w) << 16) | f2bf(f.z);
    *reinterpret_cast<uint2*>(&xs[row*200 + c4]) = make_uint2(lo, hi);
  }
  for (int c = tid; c < 64*12; c += 512)
    xs[(c/12)*200 + 180 + (c%12)] = 0;
  __syncthreads();

  const int wave = tid >> 6, lane = tid & 63;
  const int wm = wave >> 2, wn = wave & 3;
  const int l16 = lane & 15, lq = lane >> 4;

  f32x4 acc[2][9];
  #pragma unroll
  for (int i = 0; i < 2; i++)
    #pragma unroll
    for (int j = 0; j < 9; j++) acc[i][j] = f32x4{0.f,0.f,0.f,0.f};

  #pragma unroll
  for (int ks = 0; ks < 6; ks++){
    const int k0 = ks*32 + lq*8;
    bf16x8 a0 = *reinterpret_cast<const bf16x8*>(&xs[(wm*32 +      l16)*200 + k0]);
    bf16x8 a1 = *reinterpret_cast<const bf16x8*>(&xs[(wm*32 + 16 + l16)*200 + k0]);
    #pragma unroll
    for (int ct = 0; ct < 9; ct++){
      bf16x8 bw = *reinterpret_cast<const bf16x8*>(
          wqkvP + ((size_t)((wn*9 + ct)*6 + ks)*64 + lane)*8);   // contiguous 1KB/wave
      acc[0][ct] = mfma16(a0, bw, acc[0][ct]);
      acc[1][ct] = mfma16(a1, bw, acc[1][ct]);
    }
  }

  const int b = blockIdx.x >> 1;
  const int half = blockIdx.x & 1;
  const float scale = 0.18257418583505536f;   // 1/sqrt(30)

  // epilogue: four 16-row quarter passes through small LDS staging
  for (int hp = 0; hp < 4; hp++){
    __syncthreads();    // xs dead (first pass) / prev quarter's reads done
    if (wm == (hp >> 1)){
      const int rt = hp & 1;
      #pragma unroll
      for (int ct = 0; ct < 9; ct++){
        const int gt = wn*9 + ct;           // 0..35
        const int seg = gt >> 1;            // 0..17
        const int d = (gt & 1)*16 + l16;    // 0..31
        const int sel = seg / NH, hh = seg % NH;
        float bias = (d < HD) ? b_qkv[sel*DIMX + hh*HD + d] : 0.f;
        #pragma unroll
        for (int r = 0; r < 4; r++){
          const int rloc = lq*4 + r;        // 0..15
          float v = acc[rt][ct][r];
          if (d < HD) v += bias;
          if (sel == 0) v *= scale;
          ushort_t hv = f2bf(v);
          if (sel < 2) cqk[rloc*392 + seg*32 + d] = hv;
          else         cv[((seg - 12)*32 + d)*24 + rloc] = hv;
        }
      }
    }
    __syncthreads();
    const int grow = half*64 + hp*16;
    for (int c = tid; c < 768; c += 512){       // Q,K: 12 segs x 16 rows x 4 chunks
      int s = c >> 6, rem = c & 63;
      int nl = rem >> 2, dc = rem & 3;
      bf16x8 vdat = *reinterpret_cast<const bf16x8*>(&cqk[nl*392 + s*32 + dc*8]);
      ushort_t* dst = (s < NH) ? Qo : Ko;
      int hh = (s < NH) ? s : s - NH;
      *reinterpret_cast<bf16x8*>(
        &dst[(((size_t)b*NH + hh)*NTOK + grow + nl)*32 + dc*8]) = vdat;
    }
    for (int c = tid; c < 384; c += 512){       // V^T: 192 rows x 2 chunks
      int vr = c >> 1, nc = c & 1;
      bf16x8 vdat = *reinterpret_cast<const bf16x8*>(&cv[vr*24 + nc*8]);
      *reinterpret_cast<bf16x8*>(
        &Vo[((size_t)b*192 + vr)*NTOK + grow + nc*8]) = vdat;
    }
  }
}

// ---------------- attention + FC ----------------
// grid 1024 (one window), 512 thr, 8 waves x 16 q-rows.
// LDS 78336 B: ao [128][196]; k [128][36]; v [32][136]; p 8x[16][40];
// FC: wf chunk [192][64] swizzled aliased over k/v/p; out-bounce fp32 [64][188] over ao.
__global__ __launch_bounds__(512, 4) void attn_kernel(
    const ushort_t* __restrict__ Qo, const ushort_t* __restrict__ Ko, const ushort_t* __restrict__ Vo,
    const ushort_t* __restrict__ bias_p, const ushort_t* __restrict__ wfcP,
    const float* __restrict__ b_fc, float* __restrict__ out)
{
  extern __shared__ ushort_t sm2[];
  ushort_t* ao_s = sm2;            // [128][196]
  ushort_t* k_s  = sm2 + 25088;    // [128][36]
  ushort_t* v_s  = sm2 + 29696;    // [32][136]
  ushort_t* p_s  = sm2 + 34048;    // 8 x [16][40]
  ushort_t* wf_s = sm2 + 25088;    // [12288] swizzled chunk (alias)
  float*    ob   = reinterpret_cast<float*>(sm2);   // [64][188] f32 (alias over ao)

  const int tid = threadIdx.x;
  const int b = blockIdx.x;
  const int wk = b & (NWIN-1);
  const int wave = tid >> 6, lane = tid & 63;
  const int l16 = lane & 15, lq = lane >> 4;
  const int wbase = wave * 16;

  // zero FC K-pad cols of ao
  for (int i = lane; i < 256; i += 64){
    int rr = i >> 4, cc = i & 15;
    ao_s[(wbase + rr)*196 + 180 + cc] = 0;
  }

  for (int h = 0; h < NH; h++){
    __syncthreads();
    {
      const ushort_t* kg = Ko + ((size_t)b*NH + h)*NTOK*32;
      int row = tid >> 2, part = tid & 3;
      *reinterpret_cast<bf16x8*>(&k_s[row*36 + part*8]) =
        *reinterpret_cast<const bf16x8*>(kg + row*32 + part*8);
    }
    {
      const ushort_t* vg = Vo + ((size_t)b*NH + h)*32*NTOK;
      int row = tid >> 4, part = tid & 15;
      *reinterpret_cast<bf16x8*>(&v_s[row*136 + part*8]) =
        *reinterpret_cast<const bf16x8*>(vg + row*NTOK + part*8);
    }
    __syncthreads();

    // QK^T (scale folded into Q)
    bf16x8 aq = *reinterpret_cast<const bf16x8*>(
        Qo + (((size_t)b*NH + h)*NTOK + wbase + l16)*32 + lq*8);
    f32x4 s[8];
    #pragma unroll
    for (int t = 0; t < 8; t++){
      bf16x8 bk = *reinterpret_cast<const bf16x8*>(&k_s[(t*16 + l16)*36 + lq*8]);
      s[t] = mfma16(aq, bk, f32x4{0.f,0.f,0.f,0.f});
    }
    {
      const ushort_t* bp = bias_p + (((size_t)(wk*NH + h)*8 + wave)*64 + lane)*32;
      #pragma unroll
      for (int c = 0; c < 4; c++){
        bf16x8 bbv = *reinterpret_cast<const bf16x8*>(bp + c*8);
        #pragma unroll
        for (int r = 0; r < 4; r++){
          s[2*c][r]   += (float)bbv[r];
          s[2*c+1][r] += (float)bbv[4+r];
        }
      }
    }

    // wave-parallel softmax per row
    #pragma unroll
    for (int r = 0; r < 4; r++){
      float m = s[0][r];
      #pragma unroll
      for (int t = 1; t < 8; t++) m = fmaxf(m, s[t][r]);
      #pragma unroll
      for (int off = 1; off < 16; off <<= 1) m = fmaxf(m, __shfl_xor(m, off));
      float sum = 0.f;
      #pragma unroll
      for (int t = 0; t < 8; t++){
        float e = __expf(s[t][r] - m);
        s[t][r] = e; sum += e;
      }
      #pragma unroll
      for (int off = 1; off < 16; off <<= 1) sum += __shfl_xor(sum, off);
      float inv = 1.0f / sum;
      #pragma unroll
      for (int t = 0; t < 8; t++) s[t][r] *= inv;
    }

    // PV in 4 k-quarters via per-wave P buffer
    ushort_t* pw = p_s + wave*640;
    f32x4 po[2] = { f32x4{0.f,0.f,0.f,0.f}, f32x4{0.f,0.f,0.f,0.f} };
    #pragma unroll
    for (int q = 0; q < 4; q++){
      #pragma unroll
      for (int r = 0; r < 4; r++){
        #pragma unroll
        for (int t2 = 0; t2 < 2; t2++)
          pw[(lq*4 + r)*40 + t2*16 + l16] = f2bf(s[2*q + t2][r]);
      }
      bf16x8 ap = *reinterpret_cast<const bf16x8*>(&pw[l16*40 + lq*8]);
      #pragma unroll
      for (int ct = 0; ct < 2; ct++){
        bf16x8 bv = *reinterpret_cast<const bf16x8*>(&v_s[(ct*16 + l16)*136 + q*32 + lq*8]);
        po[ct] = mfma16(ap, bv, po[ct]);
      }
    }
    #pragma unroll
    for (int ct = 0; ct < 2; ct++){
      const int d = ct*16 + l16;
      if (d < HD){
        #pragma unroll
        for (int r = 0; r < 4; r++)
          ao_s[(wbase + lq*4 + r)*196 + h*HD + d] = f2bf(po[ct][r]);
      }
    }
  }

  // ---- FC with LDS-staged, swizzled weight chunks ----
  f32x4 acc2[12];
  #pragma unroll
  for (int j = 0; j < 12; j++) acc2[j] = f32x4{0.f,0.f,0.f,0.f};

  for (int c3 = 0; c3 < 3; c3++){
    __syncthreads();   // prev chunk reads / head-loop k,v,p reads done
    #pragma unroll
    for (int i = 0; i < 3; i++){
      int e = (i*512 + tid)*8;
      *reinterpret_cast<uint4*>(&wf_s[e]) =
          *reinterpret_cast<const uint4*>(&wfcP[c3*12288 + e]);
    }
    __syncthreads();
    #pragma unroll
    for (int ks2 = 0; ks2 < 2; ks2++){
      const int klocal = ks2*32 + lq*8;
      bf16x8 af = *reinterpret_cast<const bf16x8*>(
          &ao_s[(wbase + l16)*196 + c3*64 + klocal]);
      #pragma unroll
      for (int ct = 0; ct < 12; ct++){
        const int oc = ct*16 + l16;
        const int idx = (oc*64 + klocal) ^ ((oc & 7) << 3);
        bf16x8 bw = *reinterpret_cast<const bf16x8*>(&wf_s[idx]);
        acc2[ct] = mfma16(af, bw, acc2[ct]);
      }
    }
  }

  // ---- out via fp32 LDS bounce -> coalesced float4 stores ----
  for (int hp = 0; hp < 2; hp++){
    __syncthreads();   // ao/wf reads done (first) / prev half stores done
    if ((wave >> 2) == hp){
      const int wl = wave & 3;
      #pragma unroll
      for (int ct = 0; ct < 12; ct++){
        const int col = ct*16 + l16;
        if (col < DIMX){
          const float bb = b_fc[col];
          #pragma unroll
          for (int r = 0; r < 4; r++)
            ob[(wl*16 + lq*4 + r)*188 + col] = acc2[ct][r] + bb;
        }
      }
    }
    __syncthreads();
    for (int c = tid; c < 2880; c += 512){
      int row = c / 45, cc = (c % 45)*4;
      float4 v = *reinterpret_cast<const float4*>(&ob[row*188 + cc]);
      *reinterpret_cast<float4*>(
          &out[((size_t)b*NTOK + hp*64 + row)*DIMX + cc]) = v;
    }
  }
}

// ---------------- launch ----------------
extern "C" void kernel_launch(void* const* d_in, const int* in_sizes, int n_in,
                              void* d_out, int out_size, void* d_ws, size_t ws_size,
                              hipStream_t stream)
{
  const float* x      = (const float*)d_in[0];
  const float* w_qkv  = (const float*)d_in[1];
  const float* b_qkv  = (const float*)d_in[2];
  const float* w_fc   = (const float*)d_in[3];
  const float* b_fc   = (const float*)d_in[4];
  const float* rpt    = (const float*)d_in[5];
  const float* mask   = (const float*)d_in[6];
  const int*   rpi    = (const int*)d_in[7];
  float* out = (float*)d_out;

  char* ws = (char*)d_ws;
  // layout (bytes):
  //   0         wqkvP   216*64*8*2 = 221184
  //   221184    wfcP    3*12288*2  = 73728
  //   294912    bias_p  64*6*8*64*32*2 = 12582912
  //   12877824  Qo      1024*6*128*32*2 = 50331648
  //   63209472  Ko      50331648
  //   113541120 Vo      50331648   -> total 163872768
  if (ws_size < (size_t)163872768) return;
  ushort_t* wqkvP  = (ushort_t*)(ws);
  ushort_t* wfcP   = (ushort_t*)(ws + 221184);
  ushort_t* bias_p = (ushort_t*)(ws + 294912);
  ushort_t* Qo     = (ushort_t*)(ws + 12877824);
  ushort_t* Ko     = (ushort_t*)(ws + 63209472);
  ushort_t* Vo     = (ushort_t*)(ws + 113541120);

  hipLaunchKernelGGL(prep_wqkv, dim3(216), dim3(64), 0, stream, w_qkv, wqkvP);
  hipLaunchKernelGGL(prep_wfc,  dim3(192), dim3(192), 0, stream, w_fc, wfcP);
  hipLaunchKernelGGL(prep_bias, dim3(NWIN*NH*8), dim3(512), 0, stream, rpt, mask, rpi, bias_p);

  hipLaunchKernelGGL(qkv_kernel, dim3(2048), dim3(512), 0, stream,
                     x, wqkvP, b_qkv, Qo, Ko, Vo);

  (void)hipFuncSetAttribute((const void*)attn_kernel,
                            hipFuncAttributeMaxDynamicSharedMemorySize, 78336);
  hipLaunchKernelGGL(attn_kernel, dim3(1024), dim3(512), 78336, stream,
                     Qo, Ko, Vo, bias_p, wfcP, b_fc, out);
}

// Round 5
// 265.430 us; speedup vs baseline: 1.3934x; 1.3934x over previous
//
#include <hip/hip_runtime.h>

typedef unsigned short ushort_t;
typedef unsigned int uint32;
typedef __bf16 bf16x8 __attribute__((ext_vector_type(8)));
typedef float f32x4 __attribute__((ext_vector_type(4)));

#define NTOK 128
#define DIMX 180
#define NH 6
#define HD 30
#define KP 192
#define NWIN 64

__device__ __forceinline__ ushort_t f2bf(float f){
  uint32 u = __float_as_uint(f);
  u += 0x7FFFu + ((u >> 16) & 1u);
  return (ushort_t)(u >> 16);
}
__device__ __forceinline__ float bf2f(ushort_t h){
  return __uint_as_float(((uint32)h) << 16);
}
__device__ __forceinline__ f32x4 mfma16(bf16x8 a, bf16x8 b, f32x4 c){
  return __builtin_amdgcn_mfma_f32_16x16x32_bf16(a, b, c, 0, 0, 0);
}

// ---------------- prep kernels ----------------

// wqkvP fragment-contiguous: ((ct_g*6+ks)*64 + lane)*8 + e
//   col oc=ct_g*16+(lane&15) [oc=(sel*6+head)*32+d], k = ks*32+(lane>>4)*8+e
__global__ void prep_wqkv(const float* __restrict__ w, ushort_t* __restrict__ o){
  int blk = blockIdx.x;               // ct_g*6 + ks, 216 blocks
  int ct_g = blk / 6, ks = blk - ct_g*6;
  int lane = threadIdx.x;             // 64
  int l16 = lane & 15, lq = lane >> 4;
  int oc = ct_g*16 + l16;
  int seg = oc >> 5, dd = oc & 31;
  int sel = seg / NH, head = seg % NH;
  ushort_t vals[8];
  #pragma unroll
  for (int e = 0; e < 8; e++){
    int k = ks*32 + lq*8 + e;
    float v = 0.f;
    if (dd < HD && k < DIMX) v = w[k*(3*DIMX) + sel*DIMX + head*HD + dd];
    vals[e] = f2bf(v);
  }
  *reinterpret_cast<uint4*>(&o[((size_t)blk*64 + lane)*8]) =
      *reinterpret_cast<const uint4*>(vals);
}

// wfcP fragment-contiguous, K padded per-head to 32 (k' = h*32+d -> w_fc row h*30+d)
__global__ void prep_wfc(const float* __restrict__ w, ushort_t* __restrict__ o){
  int blk = blockIdx.x;               // ct_g*6 + ks, 72 blocks (ct_g 0..11)
  int ct_g = blk / 6, ks = blk - ct_g*6;
  int lane = threadIdx.x;
  int l16 = lane & 15, lq = lane >> 4;
  int oc = ct_g*16 + l16;
  ushort_t vals[8];
  #pragma unroll
  for (int e = 0; e < 8; e++){
    int k = ks*32 + lq*8 + e;
    int hh = k >> 5, d = k & 31;
    float v = (d < HD && oc < DIMX) ? w[(hh*HD + d)*DIMX + oc] : 0.f;
    vals[e] = f2bf(v);
  }
  *reinterpret_cast<uint4*>(&o[((size_t)blk*64 + lane)*8]) =
      *reinterpret_cast<const uint4*>(vals);
}

// bias_p in MFMA C-fragment order (proven)
__global__ void prep_bias(const float* __restrict__ rpt, const float* __restrict__ mask,
                          const int* __restrict__ rpi, ushort_t* __restrict__ o){
  int blk = blockIdx.x;            // (w*6+h)*8 + wave
  int wave = blk & 7, wh = blk >> 3;
  int h = wh % NH, w = wh / NH;
  int i = threadIdx.x;             // 512
  int lane = i >> 3, t = i & 7;
  int l16 = lane & 15, lq = lane >> 4;
  int m = t*16 + l16;
  ushort_t vals[4];
  #pragma unroll
  for (int r = 0; r < 4; r++){
    int n = wave*16 + lq*4 + r;
    float v = rpt[rpi[n*NTOK + m]*NH + h] + mask[((size_t)w*NTOK + n)*NTOK + m];
    vals[r] = f2bf(v);
  }
  *reinterpret_cast<uint2*>(&o[((size_t)blk*64 + lane)*32 + t*4]) =
      *reinterpret_cast<const uint2*>(vals);
}

// ---------------- QKV projection (round-3 epilogue + packed B-frags) ----------------
// grid 2048 (64 rows), 512 thr. LDS: xs [64][200] / cqk [64][392] + cv [192][72] aliased.
__global__ __launch_bounds__(512, 4) void qkv_kernel(
    const float* __restrict__ x, const ushort_t* __restrict__ wqkvP,
    const float* __restrict__ b_qkv,
    ushort_t* __restrict__ Qo, ushort_t* __restrict__ Ko, ushort_t* __restrict__ Vo)
{
  extern __shared__ ushort_t sm1[];
  ushort_t* xs  = sm1;
  ushort_t* cqk = sm1;
  ushort_t* cv  = sm1 + 25088;

  const int tid = threadIdx.x;
  const float* xb = x + (size_t)blockIdx.x * 64 * DIMX;

  for (int c = tid; c < 64*45; c += 512){
    int row = c / 45, c4 = (c % 45) * 4;
    float4 f = reinterpret_cast<const float4*>(xb)[c];
    uint32 lo = ((uint32)f2bf(f.y) << 16) | f2bf(f.x);
    uint32 hi = ((uint32)f2bf(f.w) << 16) | f2bf(f.z);
    *reinterpret_cast<uint2*>(&xs[row*200 + c4]) = make_uint2(lo, hi);
  }
  for (int c = tid; c < 64*12; c += 512)
    xs[(c/12)*200 + 180 + (c%12)] = 0;
  __syncthreads();

  const int wave = tid >> 6, lane = tid & 63;
  const int wm = wave >> 2, wn = wave & 3;
  const int l16 = lane & 15, lq = lane >> 4;

  f32x4 acc[2][9];
  #pragma unroll
  for (int i = 0; i < 2; i++)
    #pragma unroll
    for (int j = 0; j < 9; j++) acc[i][j] = f32x4{0.f,0.f,0.f,0.f};

  #pragma unroll
  for (int ks = 0; ks < 6; ks++){
    const int k0 = ks*32 + lq*8;
    bf16x8 a0 = *reinterpret_cast<const bf16x8*>(&xs[(wm*32 +      l16)*200 + k0]);
    bf16x8 a1 = *reinterpret_cast<const bf16x8*>(&xs[(wm*32 + 16 + l16)*200 + k0]);
    #pragma unroll
    for (int ct = 0; ct < 9; ct++){
      bf16x8 bw = *reinterpret_cast<const bf16x8*>(
          wqkvP + ((size_t)((wn*9 + ct)*6 + ks)*64 + lane)*8);   // contiguous 1KB/wave
      acc[0][ct] = mfma16(a0, bw, acc[0][ct]);
      acc[1][ct] = mfma16(a1, bw, acc[1][ct]);
    }
  }
  __syncthreads();   // xs dead

  const float scale = 0.18257418583505536f;   // 1/sqrt(30)
  #pragma unroll
  for (int ct = 0; ct < 9; ct++){
    const int gt = wn*9 + ct;           // 0..35
    const int seg = gt >> 1;            // 0..17
    const int d = (gt & 1)*16 + l16;    // 0..31
    const int sel = seg / NH, hh = seg % NH;
    float bias = (d < HD) ? b_qkv[sel*DIMX + hh*HD + d] : 0.f;
    #pragma unroll
    for (int rt = 0; rt < 2; rt++){
      #pragma unroll
      for (int r = 0; r < 4; r++){
        const int row = wm*32 + rt*16 + lq*4 + r;
        float v = acc[rt][ct][r];
        if (d < HD) v += bias;
        if (sel == 0) v *= scale;
        ushort_t hv = f2bf(v);
        if (sel < 2) cqk[row*392 + seg*32 + d] = hv;
        else         cv[((seg - 12)*32 + d)*72 + row] = hv;
      }
    }
  }
  __syncthreads();

  // full-line coalesced stores
  const int b = blockIdx.x >> 1;
  const int half = blockIdx.x & 1;
  for (int c = tid; c < 3072; c += 512){        // Q,K: 12 segs x 64 rows x 4 chunks
    int s = c >> 8, rem = c & 255;
    int nl = rem >> 2, dc = rem & 3;
    bf16x8 vdat = *reinterpret_cast<const bf16x8*>(&cqk[nl*392 + s*32 + dc*8]);
    ushort_t* dst = (s < NH) ? Qo : Ko;
    int hh = (s < NH) ? s : s - NH;
    *reinterpret_cast<bf16x8*>(
      &dst[(((size_t)b*NH + hh)*NTOK + half*64 + nl)*32 + dc*8]) = vdat;
  }
  for (int c = tid; c < 1536; c += 512){        // V^T: 192 rows x 8 chunks (128B/row)
    int vr = c >> 3, nc = c & 7;
    bf16x8 vdat = *reinterpret_cast<const bf16x8*>(&cv[vr*72 + nc*8]);
    *reinterpret_cast<bf16x8*>(
      &Vo[((size_t)b*192 + vr)*NTOK + half*64 + nc*8]) = vdat;
  }
}

// ---------------- attention (no FC), double-buffered K/V, ao -> Ko region ----------------
// grid 1024, 512 thr, 8 waves x 16 q-rows. LDS 46080 B:
//   k[2] @0/4608 [128][36]; v[2] @9216/13568 [32][136]; p @17920 8x[16][40]
__global__ __launch_bounds__(512, 4) void attn_kernel(
    const ushort_t* __restrict__ Qo, const ushort_t* __restrict__ Ko,
    const ushort_t* __restrict__ Vo, const ushort_t* __restrict__ bias_p,
    ushort_t* __restrict__ aoW)     // == Ko (head region reused after consumption)
{
  __shared__ ushort_t sm[23040];
  const int tid = threadIdx.x;
  const int b = blockIdx.x;
  const int wk = b & (NWIN-1);
  const int wave = tid >> 6, lane = tid & 63;
  const int l16 = lane & 15, lq = lane >> 4;
  const int wbase = wave * 16;
  const int krow = tid >> 2, kpart = tid & 3;
  const int vrow = tid >> 4, vpart = tid & 15;
  ushort_t* pw = sm + 17920 + wave*640;

  // head 0 staging
  *reinterpret_cast<bf16x8*>(&sm[krow*36 + kpart*8]) =
      *reinterpret_cast<const bf16x8*>(Ko + (size_t)b*NH*NTOK*32 + krow*32 + kpart*8);
  *reinterpret_cast<bf16x8*>(&sm[9216 + vrow*136 + vpart*8]) =
      *reinterpret_cast<const bf16x8*>(Vo + (size_t)b*NH*32*NTOK + vrow*NTOK + vpart*8);
  bf16x8 aq = *reinterpret_cast<const bf16x8*>(
      Qo + ((size_t)b*NH*NTOK + wbase + l16)*32 + lq*8);
  bf16x8 bb[4];
  {
    const ushort_t* bp = bias_p + (((size_t)wk*NH*8 + wave)*64 + lane)*32;
    #pragma unroll
    for (int c = 0; c < 4; c++) bb[c] = *reinterpret_cast<const bf16x8*>(bp + c*8);
  }
  __syncthreads();

  for (int h = 0; h < NH; h++){
    const int cur = h & 1;
    ushort_t* k_cur = sm + (cur ? 4608 : 0);
    ushort_t* v_cur = sm + 9216 + (cur ? 4352 : 0);
    ushort_t* k_nxt = sm + (cur ? 0 : 4608);
    ushort_t* v_nxt = sm + 9216 + (cur ? 0 : 4352);

    // prefetch next head (issue-early, write-late)
    bf16x8 kreg = {}, vreg = {}, aq_n = {};
    bf16x8 bbn[4] = {};
    if (h < NH-1){
      kreg = *reinterpret_cast<const bf16x8*>(
          Ko + ((size_t)b*NH + h+1)*NTOK*32 + krow*32 + kpart*8);
      vreg = *reinterpret_cast<const bf16x8*>(
          Vo + ((size_t)b*NH + h+1)*32*NTOK + vrow*NTOK + vpart*8);
      aq_n = *reinterpret_cast<const bf16x8*>(
          Qo + (((size_t)b*NH + h+1)*NTOK + wbase + l16)*32 + lq*8);
      const ushort_t* bp = bias_p + (((size_t)(wk*NH + h+1)*8 + wave)*64 + lane)*32;
      #pragma unroll
      for (int c = 0; c < 4; c++) bbn[c] = *reinterpret_cast<const bf16x8*>(bp + c*8);
    }

    // QK^T (scale folded into Q)
    f32x4 s[8];
    #pragma unroll
    for (int t = 0; t < 8; t++){
      bf16x8 bk = *reinterpret_cast<const bf16x8*>(&k_cur[(t*16 + l16)*36 + lq*8]);
      s[t] = mfma16(aq, bk, f32x4{0.f,0.f,0.f,0.f});
    }
    #pragma unroll
    for (int c = 0; c < 4; c++)
      #pragma unroll
      for (int r = 0; r < 4; r++){
        s[2*c][r]   += (float)bb[c][r];
        s[2*c+1][r] += (float)bb[c][4+r];
      }

    // wave-parallel softmax per row
    #pragma unroll
    for (int r = 0; r < 4; r++){
      float m = s[0][r];
      #pragma unroll
      for (int t = 1; t < 8; t++) m = fmaxf(m, s[t][r]);
      #pragma unroll
      for (int off = 1; off < 16; off <<= 1) m = fmaxf(m, __shfl_xor(m, off));
      float sum = 0.f;
      #pragma unroll
      for (int t = 0; t < 8; t++){
        float e = __expf(s[t][r] - m);
        s[t][r] = e; sum += e;
      }
      #pragma unroll
      for (int off = 1; off < 16; off <<= 1) sum += __shfl_xor(sum, off);
      float inv = 1.0f / sum;
      #pragma unroll
      for (int t = 0; t < 8; t++) s[t][r] *= inv;
    }

    // PV in 4 k-quarters via per-wave P buffer
    f32x4 po[2] = { f32x4{0.f,0.f,0.f,0.f}, f32x4{0.f,0.f,0.f,0.f} };
    #pragma unroll
    for (int q = 0; q < 4; q++){
      #pragma unroll
      for (int r = 0; r < 4; r++)
        #pragma unroll
        for (int t2 = 0; t2 < 2; t2++)
          pw[(lq*4 + r)*40 + t2*16 + l16] = f2bf(s[2*q + t2][r]);
      bf16x8 ap = *reinterpret_cast<const bf16x8*>(&pw[l16*40 + lq*8]);
      #pragma unroll
      for (int ct = 0; ct < 2; ct++){
        bf16x8 bv = *reinterpret_cast<const bf16x8*>(&v_cur[(ct*16 + l16)*136 + q*32 + lq*8]);
        po[ct] = mfma16(ap, bv, po[ct]);
      }
    }

    // po -> pw bounce -> coalesced 1KB/wave store into consumed Ko[b][h]
    #pragma unroll
    for (int ct = 0; ct < 2; ct++)
      #pragma unroll
      for (int r = 0; r < 4; r++)
        pw[(lq*4 + r)*40 + ct*16 + l16] = f2bf(po[ct][r]);   // cols 30/31 are exact 0
    {
      bf16x8 vv = *reinterpret_cast<const bf16x8*>(&pw[(lane>>2)*40 + (lane&3)*8]);
      *reinterpret_cast<bf16x8*>(
        aoW + (((size_t)b*NH + h)*NTOK + wbase + (lane>>2))*32 + (lane&3)*8) = vv;
    }

    // write-late staging of next head
    if (h < NH-1){
      *reinterpret_cast<bf16x8*>(&k_nxt[krow*36 + kpart*8]) = kreg;
      *reinterpret_cast<bf16x8*>(&v_nxt[vrow*136 + vpart*8]) = vreg;
      aq = aq_n;
      #pragma unroll
      for (int c = 0; c < 4; c++) bb[c] = bbn[c];
    }
    __syncthreads();
  }
}

// ---------------- FC GEMM: out = ao @ w_fc + b_fc ----------------
// grid 2048 (64 rows), 512 thr. aoP layout = Ko: [b][h][128][32].
__global__ __launch_bounds__(512, 4) void fc_kernel(
    const ushort_t* __restrict__ aoP, const ushort_t* __restrict__ wfcP,
    const float* __restrict__ b_fc, float* __restrict__ out)
{
  __shared__ ushort_t xs[64*200];
  const int tid = threadIdx.x;
  const int blk = blockIdx.x;
  const int b = blk >> 1, half = blk & 1;

  for (int c = tid; c < 1536; c += 512){
    int row = c / 24, t = c % 24;
    int hh = t >> 2, dc = t & 3;
    *reinterpret_cast<bf16x8*>(&xs[row*200 + t*8]) =
      *reinterpret_cast<const bf16x8*>(
        aoP + (((size_t)b*NH + hh)*NTOK + half*64 + row)*32 + dc*8);
  }
  __syncthreads();

  const int wave = tid >> 6, lane = tid & 63;
  const int wm = wave >> 2, wn = wave & 3;
  const int l16 = lane & 15, lq = lane >> 4;

  f32x4 acc[2][3];
  #pragma unroll
  for (int i = 0; i < 2; i++)
    #pragma unroll
    for (int j = 0; j < 3; j++) acc[i][j] = f32x4{0.f,0.f,0.f,0.f};

  #pragma unroll
  for (int ks = 0; ks < 6; ks++){
    const int k0 = ks*32 + lq*8;
    bf16x8 a0 = *reinterpret_cast<const bf16x8*>(&xs[(wm*32 +      l16)*200 + k0]);
    bf16x8 a1 = *reinterpret_cast<const bf16x8*>(&xs[(wm*32 + 16 + l16)*200 + k0]);
    #pragma unroll
    for (int ct = 0; ct < 3; ct++){
      bf16x8 bw = *reinterpret_cast<const bf16x8*>(
          wfcP + ((size_t)((wn*3 + ct)*6 + ks)*64 + lane)*8);
      acc[0][ct] = mfma16(a0, bw, acc[0][ct]);
      acc[1][ct] = mfma16(a1, bw, acc[1][ct]);
    }
  }

  #pragma unroll
  for (int ct = 0; ct < 3; ct++){
    const int col = (wn*3 + ct)*16 + l16;
    if (col < DIMX){
      const float bfc = b_fc[col];
      #pragma unroll
      for (int rt = 0; rt < 2; rt++)
        #pragma unroll
        for (int r = 0; r < 4; r++){
          const size_t grow = (size_t)blk*64 + wm*32 + rt*16 + lq*4 + r;
          out[grow*DIMX + col] = acc[rt][ct][r] + bfc;
        }
    }
  }
}

// ---------------- launch ----------------
extern "C" void kernel_launch(void* const* d_in, const int* in_sizes, int n_in,
                              void* d_out, int out_size, void* d_ws, size_t ws_size,
                              hipStream_t stream)
{
  const float* x      = (const float*)d_in[0];
  const float* w_qkv  = (const float*)d_in[1];
  const float* b_qkv  = (const float*)d_in[2];
  const float* w_fc   = (const float*)d_in[3];
  const float* b_fc   = (const float*)d_in[4];
  const float* rpt    = (const float*)d_in[5];
  const float* mask   = (const float*)d_in[6];
  const int*   rpi    = (const int*)d_in[7];
  float* out = (float*)d_out;

  char* ws = (char*)d_ws;
  // layout (bytes):
  //   0         wqkvP   216*64*8*2 = 221184
  //   221184    wfcP    72*64*8*2  = 73728
  //   294912    bias_p  12582912
  //   12877824  Qo      50331648
  //   63209472  Ko      50331648   (reused as attention-output aoP)
  //   113541120 Vo      50331648   -> total 163872768
  if (ws_size < (size_t)163872768) return;
  ushort_t* wqkvP  = (ushort_t*)(ws);
  ushort_t* wfcP   = (ushort_t*)(ws + 221184);
  ushort_t* bias_p = (ushort_t*)(ws + 294912);
  ushort_t* Qo     = (ushort_t*)(ws + 12877824);
  ushort_t* Ko     = (ushort_t*)(ws + 63209472);
  ushort_t* Vo     = (ushort_t*)(ws + 113541120);

  hipLaunchKernelGGL(prep_wqkv, dim3(216), dim3(64), 0, stream, w_qkv, wqkvP);
  hipLaunchKernelGGL(prep_wfc,  dim3(72),  dim3(64), 0, stream, w_fc, wfcP);
  hipLaunchKernelGGL(prep_bias, dim3(NWIN*NH*8), dim3(512), 0, stream, rpt, mask, rpi, bias_p);

  (void)hipFuncSetAttribute((const void*)qkv_kernel,
                            hipFuncAttributeMaxDynamicSharedMemorySize, 77824);
  hipLaunchKernelGGL(qkv_kernel, dim3(2048), dim3(512), 77824, stream,
                     x, wqkvP, b_qkv, Qo, Ko, Vo);

  hipLaunchKernelGGL(attn_kernel, dim3(1024), dim3(512), 0, stream,
                     Qo, Ko, Vo, bias_p, Ko /*aoW*/);

  hipLaunchKernelGGL(fc_kernel, dim3(2048), dim3(512), 0, stream,
                     Ko /*aoP*/, wfcP, b_fc, out);
}

// Round 7
// 263.345 us; speedup vs baseline: 1.4044x; 1.0079x over previous
//
#include <hip/hip_runtime.h>

typedef unsigned short ushort_t;
typedef unsigned int uint32;
typedef __bf16 bf16x8 __attribute__((ext_vector_type(8)));
typedef float f32x4 __attribute__((ext_vector_type(4)));

#define NTOK 128
#define DIMX 180
#define NH 6
#define HD 30
#define KP 192
#define NWIN 64

__device__ __forceinline__ ushort_t f2bf(float f){
  uint32 u = __float_as_uint(f);
  u += 0x7FFFu + ((u >> 16) & 1u);
  return (ushort_t)(u >> 16);
}
__device__ __forceinline__ float bf2f(ushort_t h){
  return __uint_as_float(((uint32)h) << 16);
}
__device__ __forceinline__ f32x4 mfma16(bf16x8 a, bf16x8 b, f32x4 c){
  return __builtin_amdgcn_mfma_f32_16x16x32_bf16(a, b, c, 0, 0, 0);
}

// ---------------- prep kernels ----------------

// wqkvP fragment-contiguous: ((ct_g*6+ks)*64 + lane)*8 + e
__global__ void prep_wqkv(const float* __restrict__ w, ushort_t* __restrict__ o){
  int blk = blockIdx.x;               // ct_g*6 + ks, 216 blocks
  int ct_g = blk / 6, ks = blk - ct_g*6;
  int lane = threadIdx.x;             // 64
  int l16 = lane & 15, lq = lane >> 4;
  int oc = ct_g*16 + l16;
  int seg = oc >> 5, dd = oc & 31;
  int sel = seg / NH, head = seg % NH;
  ushort_t vals[8];
  #pragma unroll
  for (int e = 0; e < 8; e++){
    int k = ks*32 + lq*8 + e;
    float v = 0.f;
    if (dd < HD && k < DIMX) v = w[k*(3*DIMX) + sel*DIMX + head*HD + dd];
    vals[e] = f2bf(v);
  }
  *reinterpret_cast<uint4*>(&o[((size_t)blk*64 + lane)*8]) =
      *reinterpret_cast<const uint4*>(vals);
}

// wfcP fragment-contiguous, K padded per-head to 32
__global__ void prep_wfc(const float* __restrict__ w, ushort_t* __restrict__ o){
  int blk = blockIdx.x;               // ct_g*6 + ks, 72 blocks
  int ct_g = blk / 6, ks = blk - ct_g*6;
  int lane = threadIdx.x;
  int l16 = lane & 15, lq = lane >> 4;
  int oc = ct_g*16 + l16;
  ushort_t vals[8];
  #pragma unroll
  for (int e = 0; e < 8; e++){
    int k = ks*32 + lq*8 + e;
    int hh = k >> 5, d = k & 31;
    float v = (d < HD && oc < DIMX) ? w[(hh*HD + d)*DIMX + oc] : 0.f;
    vals[e] = f2bf(v);
  }
  *reinterpret_cast<uint4*>(&o[((size_t)blk*64 + lane)*8]) =
      *reinterpret_cast<const uint4*>(vals);
}

// bias_p in MFMA C-fragment order
__global__ void prep_bias(const float* __restrict__ rpt, const float* __restrict__ mask,
                          const int* __restrict__ rpi, ushort_t* __restrict__ o){
  int blk = blockIdx.x;            // (w*6+h)*8 + wave
  int wave = blk & 7, wh = blk >> 3;
  int h = wh % NH, w = wh / NH;
  int i = threadIdx.x;             // 512
  int lane = i >> 3, t = i & 7;
  int l16 = lane & 15, lq = lane >> 4;
  int m = t*16 + l16;
  ushort_t vals[4];
  #pragma unroll
  for (int r = 0; r < 4; r++){
    int n = wave*16 + lq*4 + r;
    float v = rpt[rpi[n*NTOK + m]*NH + h] + mask[((size_t)w*NTOK + n)*NTOK + m];
    vals[r] = f2bf(v);
  }
  *reinterpret_cast<uint2*>(&o[((size_t)blk*64 + lane)*32 + t*4]) =
      *reinterpret_cast<const uint2*>(vals);
}

// ---------------- QKV projection ----------------
// grid 2048 (64 rows), 512 thr. LDS 51200 B (static): xs [64][200];
// epilogue two passes aliased into xs: pass A cqk [64][392]=50176B, pass B cv [192][72]=27648B.
__global__ __launch_bounds__(512, 4) void qkv_kernel(
    const float* __restrict__ x, const ushort_t* __restrict__ wqkvP,
    const float* __restrict__ b_qkv,
    ushort_t* __restrict__ Qo, ushort_t* __restrict__ Ko, ushort_t* __restrict__ Vo)
{
  __shared__ ushort_t sm1[25600];   // 51200 B
  ushort_t* xs  = sm1;            // [64][200]
  ushort_t* cqk = sm1;            // [64][392]  (pass A alias, 25088 ush)
  ushort_t* cv  = sm1;            // [192][72]  (pass B alias, 13824 ush)

  const int tid = threadIdx.x;
  const float* xb = x + (size_t)blockIdx.x * 64 * DIMX;

  for (int c = tid; c < 64*45; c += 512){
    int row = c / 45, c4 = (c % 45) * 4;
    float4 f = reinterpret_cast<const float4*>(xb)[c];
    uint32 lo = ((uint32)f2bf(f.y) << 16) | f2bf(f.x);
    uint32 hi = ((uint32)f2bf(f.w) << 16) | f2bf(f.z);
    *reinterpret_cast<uint2*>(&xs[row*200 + c4]) = make_uint2(lo, hi);
  }
  for (int c = tid; c < 64*12; c += 512)
    xs[(c/12)*200 + 180 + (c%12)] = 0;
  __syncthreads();

  const int wave = tid >> 6, lane = tid & 63;
  const int wm = wave >> 2, wn = wave & 3;
  const int l16 = lane & 15, lq = lane >> 4;

  f32x4 acc[2][9];
  #pragma unroll
  for (int i = 0; i < 2; i++)
    #pragma unroll
    for (int j = 0; j < 9; j++) acc[i][j] = f32x4{0.f,0.f,0.f,0.f};

  #pragma unroll
  for (int ks = 0; ks < 6; ks++){
    const int k0 = ks*32 + lq*8;
    bf16x8 a0 = *reinterpret_cast<const bf16x8*>(&xs[(wm*32 +      l16)*200 + k0]);
    bf16x8 a1 = *reinterpret_cast<const bf16x8*>(&xs[(wm*32 + 16 + l16)*200 + k0]);
    #pragma unroll
    for (int ct = 0; ct < 9; ct++){
      bf16x8 bw = *reinterpret_cast<const bf16x8*>(
          wqkvP + ((size_t)((wn*9 + ct)*6 + ks)*64 + lane)*8);   // contiguous 1KB/wave
      acc[0][ct] = mfma16(a0, bw, acc[0][ct]);
      acc[1][ct] = mfma16(a1, bw, acc[1][ct]);
    }
  }
  __syncthreads();   // xs dead

  const int b = blockIdx.x >> 1;
  const int half = blockIdx.x & 1;
  const float scale = 0.18257418583505536f;   // 1/sqrt(30)

  // ---- pass A: Q,K -> cqk ----
  #pragma unroll
  for (int ct = 0; ct < 9; ct++){
    const int gt = wn*9 + ct;           // 0..35
    const int seg = gt >> 1;            // 0..17
    if (seg < 12){
      const int d = (gt & 1)*16 + l16;  // 0..31
      const int sel = seg / NH, hh = seg % NH;
      float bias = (d < HD) ? b_qkv[sel*DIMX + hh*HD + d] : 0.f;
      #pragma unroll
      for (int rt = 0; rt < 2; rt++){
        #pragma unroll
        for (int r = 0; r < 4; r++){
          const int row = wm*32 + rt*16 + lq*4 + r;
          float v = acc[rt][ct][r];
          if (d < HD) v += bias;
          if (sel == 0) v *= scale;
          cqk[row*392 + seg*32 + d] = f2bf(v);
        }
      }
    }
  }
  __syncthreads();
  for (int c = tid; c < 3072; c += 512){        // Q,K: 12 segs x 64 rows x 4 chunks
    int s = c >> 8, rem = c & 255;
    int nl = rem >> 2, dc = rem & 3;
    bf16x8 vdat = *reinterpret_cast<const bf16x8*>(&cqk[nl*392 + s*32 + dc*8]);
    ushort_t* dst = (s < NH) ? Qo : Ko;
    int hh = (s < NH) ? s : s - NH;
    *reinterpret_cast<bf16x8*>(
      &dst[(((size_t)b*NH + hh)*NTOK + half*64 + nl)*32 + dc*8]) = vdat;
  }
  __syncthreads();   // cqk reads done

  // ---- pass B: V -> cv (transposed) ----
  #pragma unroll
  for (int ct = 0; ct < 9; ct++){
    const int gt = wn*9 + ct;
    const int seg = gt >> 1;
    if (seg >= 12){
      const int d = (gt & 1)*16 + l16;
      const int hh = seg - 12;
      float bias = (d < HD) ? b_qkv[2*DIMX + hh*HD + d] : 0.f;
      #pragma unroll
      for (int rt = 0; rt < 2; rt++){
        #pragma unroll
        for (int r = 0; r < 4; r++){
          const int row = wm*32 + rt*16 + lq*4 + r;
          float v = acc[rt][ct][r];
          if (d < HD) v += bias;
          cv[(hh*32 + d)*72 + row] = f2bf(v);
        }
      }
    }
  }
  __syncthreads();
  for (int c = tid; c < 1536; c += 512){        // V^T: 192 rows x 8 chunks
    int vr = c >> 3, nc = c & 7;
    bf16x8 vdat = *reinterpret_cast<const bf16x8*>(&cv[vr*72 + nc*8]);
    *reinterpret_cast<bf16x8*>(
      &Vo[((size_t)b*192 + vr)*NTOK + half*64 + nc*8]) = vdat;
  }
}

// ---------------- attention (no FC), double-buffered K/V, ao -> Ko region ----------------
// grid 1024, 512 thr, 8 waves x 16 q-rows. LDS 46080 B.
__global__ __launch_bounds__(512, 4) void attn_kernel(
    const ushort_t* __restrict__ Qo, const ushort_t* __restrict__ Ko,
    const ushort_t* __restrict__ Vo, const ushort_t* __restrict__ bias_p,
    ushort_t* __restrict__ aoW)     // == Ko (head region reused after consumption)
{
  __shared__ ushort_t sm[23040];
  const int tid = threadIdx.x;
  const int b = blockIdx.x;
  const int wk = b & (NWIN-1);
  const int wave = tid >> 6, lane = tid & 63;
  const int l16 = lane & 15, lq = lane >> 4;
  const int wbase = wave * 16;
  const int krow = tid >> 2, kpart = tid & 3;
  const int vrow = tid >> 4, vpart = tid & 15;
  ushort_t* pw = sm + 17920 + wave*640;

  // head 0 staging
  *reinterpret_cast<bf16x8*>(&sm[krow*36 + kpart*8]) =
      *reinterpret_cast<const bf16x8*>(Ko + (size_t)b*NH*NTOK*32 + krow*32 + kpart*8);
  *reinterpret_cast<bf16x8*>(&sm[9216 + vrow*136 + vpart*8]) =
      *reinterpret_cast<const bf16x8*>(Vo + (size_t)b*NH*32*NTOK + vrow*NTOK + vpart*8);
  bf16x8 aq = *reinterpret_cast<const bf16x8*>(
      Qo + ((size_t)b*NH*NTOK + wbase + l16)*32 + lq*8);
  bf16x8 bb[4];
  {
    const ushort_t* bp = bias_p + (((size_t)wk*NH*8 + wave)*64 + lane)*32;
    #pragma unroll
    for (int c = 0; c < 4; c++) bb[c] = *reinterpret_cast<const bf16x8*>(bp + c*8);
  }
  __syncthreads();

  for (int h = 0; h < NH; h++){
    const int cur = h & 1;
    ushort_t* k_cur = sm + (cur ? 4608 : 0);
    ushort_t* v_cur = sm + 9216 + (cur ? 4352 : 0);
    ushort_t* k_nxt = sm + (cur ? 0 : 4608);
    ushort_t* v_nxt = sm + 9216 + (cur ? 0 : 4352);

    // prefetch next head (issue-early, write-late)
    bf16x8 kreg = {}, vreg = {}, aq_n = {};
    bf16x8 bbn[4] = {};
    if (h < NH-1){
      kreg = *reinterpret_cast<const bf16x8*>(
          Ko + ((size_t)b*NH + h+1)*NTOK*32 + krow*32 + kpart*8);
      vreg = *reinterpret_cast<const bf16x8*>(
          Vo + ((size_t)b*NH + h+1)*32*NTOK + vrow*NTOK + vpart*8);
      aq_n = *reinterpret_cast<const bf16x8*>(
          Qo + (((size_t)b*NH + h+1)*NTOK + wbase + l16)*32 + lq*8);
      const ushort_t* bp = bias_p + (((size_t)(wk*NH + h+1)*8 + wave)*64 + lane)*32;
      #pragma unroll
      for (int c = 0; c < 4; c++) bbn[c] = *reinterpret_cast<const bf16x8*>(bp + c*8);
    }

    // QK^T (scale folded into Q)
    f32x4 s[8];
    #pragma unroll
    for (int t = 0; t < 8; t++){
      bf16x8 bk = *reinterpret_cast<const bf16x8*>(&k_cur[(t*16 + l16)*36 + lq*8]);
      s[t] = mfma16(aq, bk, f32x4{0.f,0.f,0.f,0.f});
    }
    #pragma unroll
    for (int c = 0; c < 4; c++)
      #pragma unroll
      for (int r = 0; r < 4; r++){
        s[2*c][r]   += (float)bb[c][r];
        s[2*c+1][r] += (float)bb[c][4+r];
      }

    // wave-parallel softmax per row
    #pragma unroll
    for (int r = 0; r < 4; r++){
      float m = s[0][r];
      #pragma unroll
      for (int t = 1; t < 8; t++) m = fmaxf(m, s[t][r]);
      #pragma unroll
      for (int off = 1; off < 16; off <<= 1) m = fmaxf(m, __shfl_xor(m, off));
      float sum = 0.f;
      #pragma unroll
      for (int t = 0; t < 8; t++){
        float e = __expf(s[t][r] - m);
        s[t][r] = e; sum += e;
      }
      #pragma unroll
      for (int off = 1; off < 16; off <<= 1) sum += __shfl_xor(sum, off);
      float inv = 1.0f / sum;
      #pragma unroll
      for (int t = 0; t < 8; t++) s[t][r] *= inv;
    }

    // PV in 4 k-quarters via per-wave P buffer
    f32x4 po[2] = { f32x4{0.f,0.f,0.f,0.f}, f32x4{0.f,0.f,0.f,0.f} };
    #pragma unroll
    for (int q = 0; q < 4; q++){
      #pragma unroll
      for (int r = 0; r < 4; r++)
        #pragma unroll
        for (int t2 = 0; t2 < 2; t2++)
          pw[(lq*4 + r)*40 + t2*16 + l16] = f2bf(s[2*q + t2][r]);
      bf16x8 ap = *reinterpret_cast<const bf16x8*>(&pw[l16*40 + lq*8]);
      #pragma unroll
      for (int ct = 0; ct < 2; ct++){
        bf16x8 bv = *reinterpret_cast<const bf16x8*>(&v_cur[(ct*16 + l16)*136 + q*32 + lq*8]);
        po[ct] = mfma16(ap, bv, po[ct]);
      }
    }

    // po -> pw bounce -> coalesced 1KB/wave store into consumed Ko[b][h]
    #pragma unroll
    for (int ct = 0; ct < 2; ct++)
      #pragma unroll
      for (int r = 0; r < 4; r++)
        pw[(lq*4 + r)*40 + ct*16 + l16] = f2bf(po[ct][r]);   // cols 30/31 exact 0
    {
      bf16x8 vv = *reinterpret_cast<const bf16x8*>(&pw[(lane>>2)*40 + (lane&3)*8]);
      *reinterpret_cast<bf16x8*>(
        aoW + (((size_t)b*NH + h)*NTOK + wbase + (lane>>2))*32 + (lane&3)*8) = vv;
    }

    // write-late staging of next head
    if (h < NH-1){
      *reinterpret_cast<bf16x8*>(&k_nxt[krow*36 + kpart*8]) = kreg;
      *reinterpret_cast<bf16x8*>(&v_nxt[vrow*136 + vpart*8]) = vreg;
      aq = aq_n;
      #pragma unroll
      for (int c = 0; c < 4; c++) bb[c] = bbn[c];
    }
    __syncthreads();
  }
}

// ---------------- FC GEMM: out = ao @ w_fc + b_fc ----------------
// grid 2048 (64 rows), 512 thr. aoP layout = Ko: [b][h][128][32].
// LDS 25600 B static: xs [64][200] bf16; epilogue ob [32][180] f32 (23040 B) aliased,
// two half-passes of 32 rows.
__global__ __launch_bounds__(512, 4) void fc_kernel(
    const ushort_t* __restrict__ aoP, const ushort_t* __restrict__ wfcP,
    const float* __restrict__ b_fc, float* __restrict__ out)
{
  __shared__ ushort_t xs[64*200];   // 25600 B
  const int tid = threadIdx.x;
  const int blk = blockIdx.x;
  const int b = blk >> 1, half = blk & 1;

  for (int c = tid; c < 1536; c += 512){
    int row = c / 24, t = c % 24;
    int hh = t >> 2, dc = t & 3;
    *reinterpret_cast<bf16x8*>(&xs[row*200 + t*8]) =
      *reinterpret_cast<const bf16x8*>(
        aoP + (((size_t)b*NH + hh)*NTOK + half*64 + row)*32 + dc*8);
  }
  __syncthreads();

  const int wave = tid >> 6, lane = tid & 63;
  const int wm = wave >> 2, wn = wave & 3;
  const int l16 = lane & 15, lq = lane >> 4;

  f32x4 acc[2][3];
  #pragma unroll
  for (int i = 0; i < 2; i++)
    #pragma unroll
    for (int j = 0; j < 3; j++) acc[i][j] = f32x4{0.f,0.f,0.f,0.f};

  #pragma unroll
  for (int ks = 0; ks < 6; ks++){
    const int k0 = ks*32 + lq*8;
    bf16x8 a0 = *reinterpret_cast<const bf16x8*>(&xs[(wm*32 +      l16)*200 + k0]);
    bf16x8 a1 = *reinterpret_cast<const bf16x8*>(&xs[(wm*32 + 16 + l16)*200 + k0]);
    #pragma unroll
    for (int ct = 0; ct < 3; ct++){
      bf16x8 bw = *reinterpret_cast<const bf16x8*>(
          wfcP + ((size_t)((wn*3 + ct)*6 + ks)*64 + lane)*8);
      acc[0][ct] = mfma16(a0, bw, acc[0][ct]);
      acc[1][ct] = mfma16(a1, bw, acc[1][ct]);
    }
  }

  // epilogue: two 32-row half-passes through fp32 bounce (fits 25600 B)
  float* ob = reinterpret_cast<float*>(xs);   // [32][180] f32 per pass
  for (int hp = 0; hp < 2; hp++){
    __syncthreads();   // xs GEMM reads done (hp=0) / prev half stores done (hp=1)
    if (wm == hp){
      #pragma unroll
      for (int ct = 0; ct < 3; ct++){
        const int col = (wn*3 + ct)*16 + l16;
        if (col < DIMX){
          const float bfc = b_fc[col];
          #pragma unroll
          for (int rt = 0; rt < 2; rt++)
            #pragma unroll
            for (int r = 0; r < 4; r++)
              ob[(rt*16 + lq*4 + r)*DIMX + col] = acc[rt][ct][r] + bfc;
        }
      }
    }
    __syncthreads();
    for (int c = tid; c < 1440; c += 512){
      int row = c / 45, cc = (c % 45)*4;
      float4 v = *reinterpret_cast<const float4*>(&ob[row*DIMX + cc]);
      *reinterpret_cast<float4*>(
          &out[((size_t)blk*64 + hp*32 + row)*DIMX + cc]) = v;
    }
  }
}

// ---------------- launch ----------------
extern "C" void kernel_launch(void* const* d_in, const int* in_sizes, int n_in,
                              void* d_out, int out_size, void* d_ws, size_t ws_size,
                              hipStream_t stream)
{
  const float* x      = (const float*)d_in[0];
  const float* w_qkv  = (const float*)d_in[1];
  const float* b_qkv  = (const float*)d_in[2];
  const float* w_fc   = (const float*)d_in[3];
  const float* b_fc   = (const float*)d_in[4];
  const float* rpt    = (const float*)d_in[5];
  const float* mask   = (const float*)d_in[6];
  const int*   rpi    = (const int*)d_in[7];
  float* out = (float*)d_out;

  char* ws = (char*)d_ws;
  // layout (bytes):
  //   0         wqkvP   216*64*8*2 = 221184
  //   221184    wfcP    72*64*8*2  = 73728
  //   294912    bias_p  12582912
  //   12877824  Qo      50331648
  //   63209472  Ko      50331648   (reused as attention-output aoP)
  //   113541120 Vo      50331648   -> total 163872768
  if (ws_size < (size_t)163872768) return;
  ushort_t* wqkvP  = (ushort_t*)(ws);
  ushort_t* wfcP   = (ushort_t*)(ws + 221184);
  ushort_t* bias_p = (ushort_t*)(ws + 294912);
  ushort_t* Qo     = (ushort_t*)(ws + 12877824);
  ushort_t* Ko     = (ushort_t*)(ws + 63209472);
  ushort_t* Vo     = (ushort_t*)(ws + 113541120);

  hipLaunchKernelGGL(prep_wqkv, dim3(216), dim3(64), 0, stream, w_qkv, wqkvP);
  hipLaunchKernelGGL(prep_wfc,  dim3(72),  dim3(64), 0, stream, w_fc, wfcP);
  hipLaunchKernelGGL(prep_bias, dim3(NWIN*NH*8), dim3(512), 0, stream, rpt, mask, rpi, bias_p);

  hipLaunchKernelGGL(qkv_kernel, dim3(2048), dim3(512), 0, stream,
                     x, wqkvP, b_qkv, Qo, Ko, Vo);

  hipLaunchKernelGGL(attn_kernel, dim3(1024), dim3(512), 0, stream,
                     Qo, Ko, Vo, bias_p, Ko /*aoW*/);

  hipLaunchKernelGGL(fc_kernel, dim3(2048), dim3(512), 0, stream,
                     Ko /*aoP*/, wfcP, b_fc, out);
}